// Round 9
// baseline (1714.655 us; speedup 1.0000x reference)
//
#include <hip/hip_runtime.h>
#include <hip/hip_bf16.h>
#include <math.h>

// FNO3D on MI355X. Inputs fp32, internal fp32, output fp32.
// B=4, C=24, 64^3 grid, modes 12^3, 4 layers.
// GroupNorm affine computed inline in each consumer from raw stats (no gnstat pass).
// k_layer processes output-channel PAIRS with <2 x float> packed FMA (v_pk_fma_f32).

static constexpr int BN = 4;
static constexpr int CW = 24;
static constexpr int ZD = 64;
static constexpr size_t NPTS = 64ull * 64 * 64;      // 262144
static constexpr int KM = 12;
static constexpr int KK2 = 144;
static constexpr int M3 = 1728;
static constexpr int NLAYERS = 4;
static constexpr float GN_N = 6291456.0f;            // CW*NPTS

typedef float v2f __attribute__((ext_vector_type(2)));
static __device__ __forceinline__ v2f mk2(float a, float b) { v2f r; r.x = a; r.y = b; return r; }

static constexpr size_t OFF_H     = 0;                                     // state A [B][C][Z][Y][X]
static constexpr size_t OFF_PRE   = OFF_H   + (size_t)BN * CW * NPTS;      // state B (ping-pong)
static constexpr size_t OFF_A1    = OFF_PRE + (size_t)BN * CW * NPTS;      // A1 [b][c][z][kx][y] cplx (shared with B2 [b][o][z][y][kx])
static constexpr size_t OFF_A2    = OFF_A1  + (size_t)BN * CW * ZD * KM * ZD * 2; // B1 [b][o][z][kk] cplx
static constexpr size_t OFF_HF    = OFF_A2  + (size_t)BN * CW * KK2 * ZD * 2;     // Hf [b][c][mode] cplx
static constexpr size_t OFF_OUT   = OFF_HF  + (size_t)BN * CW * M3 * 2;           // Out [b][o][mode] cplx
static constexpr size_t OFF_AX    = OFF_OUT + (size_t)BN * CW * M3 * 2;           // axis tables 3*24*64
static constexpr size_t OFF_STATS = OFF_AX  + 3 * CW * 64;                        // [layer][b][2]

__device__ __forceinline__ float gelu_exact(float y) {
  return 0.5f * y * (1.f + erff(y * 0.70710678118654752f));
}

// per-(b,c) GN affine from raw stats of layer lm1 (lm1 < 0 -> identity)
__device__ __forceinline__ void gn_affine(const float* stats, const float* gnw,
                                          const float* gnb, int lm1, int b, int c,
                                          float& gw, float& gb) {
  gw = 1.f; gb = 0.f;
  if (lm1 >= 0) {
    float s1 = stats[(lm1 * BN + b) * 2];
    float s2 = stats[(lm1 * BN + b) * 2 + 1];
    float mean = s1 / GN_N;
    float var = s2 / GN_N - mean * mean;
    float rstd = rsqrtf(var + 1e-5f);
    gw = gnw[lm1 * CW + c] * rstd;
    gb = gnb[lm1 * CW + c] - mean * gw;
  }
}

// ---------------- axis tables for the lift (posenc is separable) -------------
__global__ void k_axis(const float* __restrict__ lw, float* __restrict__ ws) {
  int t = blockIdx.x * blockDim.x + threadIdx.x;
  if (t >= 3 * CW * 64) return;
  int v = t & 63;
  int o = (t >> 6) % CW;
  int axis = t / (64 * CW);
  float val = -1.f + 2.f * (float)v / 63.f;
  float acc = lw[o * 54 + 3 + axis] * val;   // linear coordinate channel
  for (int k = 1; k <= 8; k++) {
    float s, c;
    sincosf((float)k * 3.14159265358979323846f * val, &s, &c);
    int base = 6 + 6 * (k - 1) + 2 * axis;
    acc += lw[o * 54 + base] * s + lw[o * 54 + base + 1] * c;
  }
  ws[OFF_AX + (size_t)axis * CW * 64 + o * 64 + v] = acc;
}

// ---------------- lift: h = W*x + a_z + a_y + a_x + b ------------------------
__global__ __launch_bounds__(64) void k_lift(const float* __restrict__ xin,
                                             const float* __restrict__ lw,
                                             const float* __restrict__ lb,
                                             float* __restrict__ ws) {
  int bid = blockIdx.x;                  // b*4096 + z*64 + y
  int b = bid >> 12, z = (bid >> 6) & 63, y = bid & 63;
  int tx = threadIdx.x;
  size_t zyx = (size_t)z * 4096 + y * 64 + tx;
  float x0 = xin[(size_t)(b * 3 + 0) * NPTS + zyx];
  float x1 = xin[(size_t)(b * 3 + 1) * NPTS + zyx];
  float x2 = xin[(size_t)(b * 3 + 2) * NPTS + zyx];
  const float* az = ws + OFF_AX;
  const float* ay = az + CW * 64;
  const float* axt = ay + CW * 64;
  float* h = ws + OFF_H;
  for (int o = 0; o < CW; o++) {
    float acc = lb[o] + lw[o * 54 + 0] * x0 + lw[o * 54 + 1] * x1 +
                lw[o * 54 + 2] * x2 + az[o * 64 + z] + ay[o * 64 + y] + axt[o * 64 + tx];
    h[(size_t)(b * CW + o) * NPTS + zyx] = acc;
  }
}

// ------- forward DFT along x (inline affine, register rotators) --------------
__global__ void k_dftx(const float* __restrict__ hsrc, float* __restrict__ A1,
                       const float* __restrict__ stats, const float* __restrict__ gnw,
                       const float* __restrict__ gnb, int layer) {
  __shared__ float pl[64][65];
  int bid = blockIdx.x;                  // bc*64 + z
  int bc = bid >> 6;
  float gw, gb;
  gn_affine(stats, gnw, gnb, layer - 1, bc / CW, bc % CW, gw, gb);
  const float* src = hsrc + (size_t)bid * 4096;
  int t = threadIdx.x;
  for (int i = t; i < 4096; i += 256) pl[i >> 6][i & 63] = fmaf(src[i], gw, gb);
  __syncthreads();
  int q = t >> 6, y = t & 63;            // thread computes modes kx = q, q+4, q+8 for row y
  float C0, S0, C1, S1, C2, S2;
  sincosf(-6.283185307179586f * (float)q / 64.f, &S0, &C0);
  sincosf(-6.283185307179586f * (float)(q + 4) / 64.f, &S1, &C1);
  sincosf(-6.283185307179586f * (float)(q + 8) / 64.f, &S2, &C2);
  float r0 = 1.f, i0 = 0.f, r1 = 1.f, i1 = 0.f, r2 = 1.f, i2 = 0.f;
  float ar0 = 0.f, ai0 = 0.f, ar1 = 0.f, ai1 = 0.f, ar2 = 0.f, ai2 = 0.f;
  const float* row = pl[y];
  for (int xx = 0; xx < 64; xx++) {
    float v = row[xx];
    ar0 = fmaf(v, r0, ar0); ai0 = fmaf(v, i0, ai0);
    ar1 = fmaf(v, r1, ar1); ai1 = fmaf(v, i1, ai1);
    ar2 = fmaf(v, r2, ar2); ai2 = fmaf(v, i2, ai2);
    float nr;
    nr = r0 * C0 - i0 * S0; i0 = fmaf(r0, S0, i0 * C0); r0 = nr;
    nr = r1 * C1 - i1 * S1; i1 = fmaf(r1, S1, i1 * C1); r1 = nr;
    nr = r2 * C2 - i2 * S2; i2 = fmaf(r2, S2, i2 * C2); r2 = nr;
  }
  float2* dst = (float2*)A1 + (size_t)bid * KM * 64;   // layout [kx][y]
  dst[t]       = make_float2(ar0, ai0);
  dst[t + 256] = make_float2(ar1, ai1);
  dst[t + 512] = make_float2(ar2, ai2);
}

// ------- fused forward DFT along y then z (one block per (bc,kx)) ------------
__global__ void k_dftyz(const float* __restrict__ A1, float* __restrict__ Hf) {
  __shared__ float in_re[64][65], in_im[64][65];
  __shared__ float o1_re[12][65], o1_im[12][65];
  int bid = blockIdx.x;                  // bc*12 + kx
  int kx = bid % 12, bc = bid / 12;
  int t = threadIdx.x;
  const float2* src = (const float2*)A1;
  for (int i = t; i < 4096; i += 256) {
    int z = i >> 6, y = i & 63;
    float2 v = src[((size_t)(bc * 64 + z)) * 768 + kx * 64 + y];
    in_re[z][y] = v.x; in_im[z][y] = v.y;
  }
  __syncthreads();
  // phase 1: y-DFT -> o1[ky][z]
  for (int i = t; i < 768; i += 256) {
    int z = i / 12, ky = i % 12;
    float C, S;
    sincosf(-6.283185307179586f * (float)ky / 64.f, &S, &C);
    float r = 1.f, ir = 0.f;
    float re = 0.f, im = 0.f;
    for (int y = 0; y < 64; y++) {
      float ar = in_re[z][y], ai = in_im[z][y];
      re += ar * r - ai * ir;
      im += ai * r + ar * ir;
      float nr = r * C - ir * S; ir = fmaf(r, S, ir * C); r = nr;
    }
    o1_re[ky][z] = re; o1_im[ky][z] = im;
  }
  __syncthreads();
  // phase 2: z-DFT -> Hf[kz][ky]
  if (t < KK2) {
    int kz = t / 12, ky = t % 12;
    float C, S;
    sincosf(-6.283185307179586f * (float)kz / 64.f, &S, &C);
    float r = 1.f, ir = 0.f;
    float re = 0.f, im = 0.f;
    for (int zz = 0; zz < 64; zz++) {
      float ar = o1_re[ky][zz], ai = o1_im[ky][zz];
      re += ar * r - ai * ir;
      im += ai * r + ar * ir;
      float nr = r * C - ir * S; ir = fmaf(r, S, ir * C); r = nr;
    }
    ((float2*)Hf)[(size_t)bc * M3 + kz * KK2 + ky * 12 + kx] = make_float2(re, im);
  }
}

// ---------------- mode mix: Out[b,o,m] = sum_c Hf[b,c,m]*W[c,o,m] ------------
__global__ void k_mix(const float* __restrict__ Hf, const float* __restrict__ specw,
                      float* __restrict__ Outb, int layer) {
  __shared__ float hre[24][64], him[24][64];
  int bid = blockIdx.x;                  // b*54 + chunk*2 + og
  int b = bid / 54, rem = bid % 54;
  int chunk = rem >> 1, og = rem & 1;
  int m0 = chunk * 64;
  int t = threadIdx.x;
  const float2* hf = (const float2*)Hf + (size_t)b * CW * M3;
  for (int i = t; i < 24 * 64; i += 256) {
    int c = i >> 6, m = i & 63;
    float2 v = hf[(size_t)c * M3 + m0 + m];
    hre[c][m] = v.x; him[c][m] = v.y;
  }
  __syncthreads();
  const float2* W2 = (const float2*)specw + (size_t)layer * 576 * M3;
  float2* outp = (float2*)Outb + (size_t)b * CW * M3;
  for (int p = t; p < 12 * 64; p += 256) {
    int o = og * 12 + (p >> 6), m = p & 63;
    int mg = m0 + m;
    float re = 0.f, im = 0.f;
    for (int c = 0; c < 24; c++) {
      float2 w = W2[(size_t)(c * 24 + o) * M3 + mg];
      float wr = w.x, wi = w.y;
      float ar = hre[c][m], ai = him[c][m];
      re += ar * wr - ai * wi;
      im += ar * wi + ai * wr;
    }
    int kx = mg % 12;
    float sc = (kx == 0 ? 1.f : 2.f) * (1.f / 262144.f);  // irfftn scale + rfft doubling
    outp[(size_t)o * M3 + mg] = make_float2(re * sc, im * sc);
  }
}

// ---------------- inverse DFT along z (register rotators) --------------------
__global__ void k_invz(const float* __restrict__ Outb, float* __restrict__ B1) {
  __shared__ float lre[1728], lim[1728];
  int bid = blockIdx.x;                  // bo*4 + zc
  int bo = bid >> 2, zc = bid & 3;
  const float2* src = (const float2*)Outb + (size_t)bo * M3;
  int t = threadIdx.x;
  for (int i = t; i < 1728; i += 256) { float2 v = src[i]; lre[i] = v.x; lim[i] = v.y; }
  __syncthreads();
  float2* dst = (float2*)B1 + (size_t)bo * 64 * KK2 + (size_t)zc * 16 * KK2;
  for (int p = t; p < 16 * KK2; p += 256) {
    int z = zc * 16 + p / KK2, kk = p % KK2;
    float C, S;
    sincosf(6.283185307179586f * (float)z / 64.f, &S, &C);
    float r = 1.f, ir = 0.f;
    float re = 0.f, im = 0.f;
    for (int kz = 0; kz < 12; kz++) {
      float ar = lre[kz * KK2 + kk], ai = lim[kz * KK2 + kk];
      re += ar * r - ai * ir;
      im += ar * ir + ai * r;
      float nr = r * C - ir * S; ir = fmaf(r, S, ir * C); r = nr;
    }
    dst[p] = make_float2(re, im);
  }
}

// ---------------- inverse DFT along y (register rotators) --------------------
__global__ void k_invy(const float* __restrict__ B1, float* __restrict__ B2) {
  __shared__ float lre[144], lim[144];
  int bid = blockIdx.x;                  // bo*64 + z
  const float2* src = (const float2*)B1 + (size_t)bid * KK2;
  int t = threadIdx.x;
  if (t < 144) { float2 v = src[t]; lre[t] = v.x; lim[t] = v.y; }
  __syncthreads();
  float2* dst = (float2*)B2 + (size_t)bid * 64 * KM;
  for (int p = t; p < 64 * KM; p += 256) {
    int y = p / KM, kx = p % KM;
    float C, S;
    sincosf(6.283185307179586f * (float)y / 64.f, &S, &C);
    float r = 1.f, ir = 0.f;
    float re = 0.f, im = 0.f;
    for (int ky = 0; ky < 12; ky++) {
      float ar = lre[ky * 12 + kx], ai = lim[ky * 12 + kx];
      re += ar * r - ai * ir;
      im += ar * ir + ai * r;
      float nr = r * C - ir * S; ir = fmaf(r, S, ir * C); r = nr;
    }
    dst[p] = make_float2(re, im);        // p = y*12+kx -> layout [y][kx]
  }
}

// ------- fused layer: o-PAIRS with packed fp32 FMA. Affine-on-load, dbuf
//         LDS halo tile pairs, inverse-x + pointwise + depthwise + gelu +
//         residual + GN sums. -----------------------------------------------
__global__ __launch_bounds__(256) void k_layer(const float* __restrict__ hsrc,
                                               const float* __restrict__ B2f,
                                               const float* __restrict__ wsw,
                                               const float* __restrict__ wsb,
                                               const float* __restrict__ locw,
                                               const float* __restrict__ locb,
                                               const float* __restrict__ gammas,
                                               const float* __restrict__ gnw,
                                               const float* __restrict__ gnb,
                                               float* __restrict__ pre,
                                               float* __restrict__ stats, int layer) {
  __shared__ __align__(16) float s_ws2[576];    // [op][c][2]  pair-packed pointwise W
  __shared__ __align__(8)  float s_loc2[1296];  // [op][tap][2] pair-packed depthwise W
  __shared__ __align__(16) float s_sp2[2304];   // [op][ty][kx][4] {re0,re1,im0,im1}
  __shared__ float s_wsb[24], s_locb[24], s_gw[24], s_gb[24];
  __shared__ float s_ch[4][18][66];             // 4 halo tiles (pair double-buffer)
  __shared__ float s_red[8];

  int bid = blockIdx.x;                  // b*1024 + z*16 + yt
  int b = bid >> 10, z = (bid >> 4) & 63, yt = bid & 15;
  int y0 = yt * 4;
  int tid = threadIdx.x;
  int tx = tid & 63, ty = tid >> 6;
  int y = y0 + ty;

  for (int i = tid; i < 576; i += 256) {               // pointwise repack
    int o = i / 24, c = i % 24;
    s_ws2[((o >> 1) * 24 + c) * 2 + (o & 1)] = wsw[layer * 576 + i];
  }
  for (int i = tid; i < 648; i += 256) {               // depthwise repack
    int o = i / 27, tap = i % 27;
    s_loc2[((o >> 1) * 27 + tap) * 2 + (o & 1)] = locw[layer * 648 + i];
  }
  const float2* b2 = (const float2*)B2f;
  for (int i = tid; i < 1152; i += 256) {              // spectral repack
    int o = i / 48, rem = i % 48;
    int tyy = rem / 12, kxx = rem % 12;
    float2 v = b2[(((size_t)(b * CW + o) * 64 + z) * 64 + (y0 + tyy)) * KM + kxx];
    int base = (((o >> 1) * 4 + tyy) * 12 + kxx) * 4;
    s_sp2[base + (o & 1)]     = v.x;
    s_sp2[base + 2 + (o & 1)] = v.y;
  }
  if (tid < 24) {
    s_wsb[tid] = wsb[layer * 24 + tid]; s_locb[tid] = locb[layer * 24 + tid];
    float gw, gb;
    gn_affine(stats, gnw, gnb, layer - 1, b, tid, gw, gb);
    s_gw[tid] = gw; s_gb[tid] = gb;
  }
  if (tid < 144) {                       // zero x-halo columns of all 4 tiles
    int bf = tid / 36, rem = tid % 36;
    s_ch[bf][rem >> 1][(rem & 1) * 65] = 0.f;
  }
  __syncthreads();

  float cs[12], sn[12];
#pragma unroll
  for (int k = 0; k < 12; k++) {
    sincosf(6.283185307179586f * (float)((k * tx) & 63) / 64.f, &sn[k], &cs[k]);
  }

  float gamma = gammas[layer];
  size_t base_b = (size_t)b * CW * NPTS;
  size_t zyx = (size_t)z * 4096 + (size_t)y * 64 + tx;

  float hreg[24];
#pragma unroll
  for (int c = 0; c < 24; c++) hreg[c] = fmaf(hsrc[base_b + (size_t)c * NPTS + zyx], s_gw[c], s_gb[c]);

  int si[5]; size_t sgo[5]; bool svalid[5];
#pragma unroll
  for (int j = 0; j < 5; j++) {
    int i = tid + j * 256;
    si[j] = i;
    int rr = i >> 6, xx = i & 63;
    int z2 = z + rr / 6 - 1, y2 = y0 + (rr % 6) - 1;
    svalid[j] = (i < 1152) && ((unsigned)z2 < 64u) && ((unsigned)y2 < 64u);
    sgo[j] = (size_t)((unsigned)z2 & 63u) * 4096 + (size_t)((unsigned)y2 & 63u) * 64 + xx;
  }

  // prologue: stage channels 0,1 into tiles 0,1
#pragma unroll
  for (int j = 0; j < 5; j++) {
    float vA = svalid[j] ? fmaf(hsrc[base_b + sgo[j]], s_gw[0], s_gb[0]) : 0.f;
    float vB = svalid[j] ? fmaf(hsrc[base_b + NPTS + sgo[j]], s_gw[1], s_gb[1]) : 0.f;
    if (si[j] < 1152) {
      s_ch[0][si[j] >> 6][(si[j] & 63) + 1] = vA;
      s_ch[1][si[j] >> 6][(si[j] & 63) + 1] = vB;
    }
  }
  __syncthreads();

  float lsum = 0.f, lsq = 0.f;
#pragma unroll 1
  for (int op = 0; op < 12; op++) {
    int tb = (op & 1) * 2;               // current tile pair
    // (a) issue next pair's loads early
    float r0=0.f,r1=0.f,r2=0.f,r3=0.f,r4=0.f,r5=0.f,r6=0.f,r7=0.f,r8=0.f,r9=0.f;
    if (op < 11) {
      size_t nbA = base_b + (size_t)(2 * op + 2) * NPTS;
      size_t nbB = nbA + NPTS;
      if (svalid[0]) { r0 = hsrc[nbA + sgo[0]]; r5 = hsrc[nbB + sgo[0]]; }
      if (svalid[1]) { r1 = hsrc[nbA + sgo[1]]; r6 = hsrc[nbB + sgo[1]]; }
      if (svalid[2]) { r2 = hsrc[nbA + sgo[2]]; r7 = hsrc[nbB + sgo[2]]; }
      if (svalid[3]) { r3 = hsrc[nbA + sgo[3]]; r8 = hsrc[nbB + sgo[3]]; }
      if (svalid[4]) { r4 = hsrc[nbA + sgo[4]]; r9 = hsrc[nbB + sgo[4]]; }
    }

    // (b) compute output pair (2op, 2op+1)
    const float* t0 = &s_ch[tb][0][0];
    const float* t1 = &s_ch[tb + 1][0][0];
    v2f dv = mk2(0.f, 0.f), wv = mk2(0.f, 0.f), sp = mk2(0.f, 0.f);
    // depthwise 3x3x3, weights pair-packed
#pragma unroll
    for (int zi = 0; zi < 3; zi++) {
#pragma unroll
      for (int yi = 0; yi < 3; yi++) {
        int ro = (zi * 6 + ty + yi) * 66 + 1 + tx;
        float a0m = t0[ro - 1], a00 = t0[ro], a0p = t0[ro + 1];
        float a1m = t1[ro - 1], a10 = t1[ro], a1p = t1[ro + 1];
        const v2f* lp = (const v2f*)&s_loc2[(op * 27 + (zi * 3 + yi) * 3) * 2];
        dv += mk2(a0m, a1m) * lp[0];
        dv += mk2(a00, a10) * lp[1];
        dv += mk2(a0p, a1p) * lp[2];
      }
    }
    // pointwise 24x24, weights pair-packed, input splatted
    const v2f* wp = (const v2f*)&s_ws2[op * 48];
#pragma unroll
    for (int c = 0; c < 24; c++) wv += wp[c] * hreg[c];
    // spectral inverse along x, coefficients pair-packed
    const float4* spp = (const float4*)&s_sp2[(op * 4 + ty) * 48];
#pragma unroll
    for (int kx = 0; kx < 12; kx++) {
      float4 q = spp[kx];
      sp += mk2(q.x, q.y) * cs[kx];
      sp -= mk2(q.z, q.w) * sn[kx];
    }
    int o0 = 2 * op, o1 = 2 * op + 1;
    float hc0 = t0[(7 + ty) * 66 + 1 + tx];
    float hc1 = t1[(7 + ty) * 66 + 1 + tx];
    v2f yv = sp + wv + dv;
    float pv0 = hc0 + gamma * gelu_exact(yv.x + s_wsb[o0] + s_locb[o0]);
    float pv1 = hc1 + gamma * gelu_exact(yv.y + s_wsb[o1] + s_locb[o1]);
    pre[base_b + (size_t)o0 * NPTS + zyx] = pv0;
    pre[base_b + (size_t)o1 * NPTS + zyx] = pv1;
    lsum += pv0 + pv1; lsq += pv0 * pv0 + pv1 * pv1;

    // (c) write staged pair (affine'd) into other tiles, then barrier
    if (op < 11) {
      int nb = tb ^ 2;
      float gwa = s_gw[o0 + 2], gba = s_gb[o0 + 2];
      float gwb = s_gw[o1 + 2], gbb = s_gb[o1 + 2];
      float wA0 = svalid[0] ? fmaf(r0, gwa, gba) : 0.f;
      float wA1 = svalid[1] ? fmaf(r1, gwa, gba) : 0.f;
      float wA2 = svalid[2] ? fmaf(r2, gwa, gba) : 0.f;
      float wA3 = svalid[3] ? fmaf(r3, gwa, gba) : 0.f;
      float wA4 = svalid[4] ? fmaf(r4, gwa, gba) : 0.f;
      float wB0 = svalid[0] ? fmaf(r5, gwb, gbb) : 0.f;
      float wB1 = svalid[1] ? fmaf(r6, gwb, gbb) : 0.f;
      float wB2 = svalid[2] ? fmaf(r7, gwb, gbb) : 0.f;
      float wB3 = svalid[3] ? fmaf(r8, gwb, gbb) : 0.f;
      float wB4 = svalid[4] ? fmaf(r9, gwb, gbb) : 0.f;
      if (si[0] < 1152) { s_ch[nb][si[0] >> 6][(si[0] & 63) + 1] = wA0; s_ch[nb + 1][si[0] >> 6][(si[0] & 63) + 1] = wB0; }
      if (si[1] < 1152) { s_ch[nb][si[1] >> 6][(si[1] & 63) + 1] = wA1; s_ch[nb + 1][si[1] >> 6][(si[1] & 63) + 1] = wB1; }
      if (si[2] < 1152) { s_ch[nb][si[2] >> 6][(si[2] & 63) + 1] = wA2; s_ch[nb + 1][si[2] >> 6][(si[2] & 63) + 1] = wB2; }
      if (si[3] < 1152) { s_ch[nb][si[3] >> 6][(si[3] & 63) + 1] = wA3; s_ch[nb + 1][si[3] >> 6][(si[3] & 63) + 1] = wB3; }
      if (si[4] < 1152) { s_ch[nb][si[4] >> 6][(si[4] & 63) + 1] = wA4; s_ch[nb + 1][si[4] >> 6][(si[4] & 63) + 1] = wB4; }
    }
    __syncthreads();
  }

  for (int off = 32; off; off >>= 1) { lsum += __shfl_down(lsum, off); lsq += __shfl_down(lsq, off); }
  if (tx == 0) { s_red[ty * 2] = lsum; s_red[ty * 2 + 1] = lsq; }
  __syncthreads();
  if (tid == 0) {
    float a = s_red[0] + s_red[2] + s_red[4] + s_red[6];
    float q = s_red[1] + s_red[3] + s_red[5] + s_red[7];
    atomicAdd(&stats[(layer * BN + b) * 2], a);
    atomicAdd(&stats[(layer * BN + b) * 2 + 1], q);
  }
}

// ---------------- projection head (inline affine) ----------------------------
__global__ __launch_bounds__(64) void k_proj(const float* __restrict__ h,
                                             const float* __restrict__ p1w,
                                             const float* __restrict__ p1b,
                                             const float* __restrict__ p2w,
                                             const float* __restrict__ p2b,
                                             const float* __restrict__ stats,
                                             const float* __restrict__ gnw,
                                             const float* __restrict__ gnb,
                                             float* __restrict__ out) {
  __shared__ float s_w[576], s_b[24], s_w2[24], s_gw[24], s_gb[24];
  int bid = blockIdx.x;
  int b = bid >> 12, z = (bid >> 6) & 63, y = bid & 63;
  int tx = threadIdx.x;
  for (int i = tx; i < 576; i += 64) s_w[i] = p1w[i];
  if (tx < 24) {
    s_b[tx] = p1b[tx]; s_w2[tx] = p2w[tx];
    float gw, gb;
    gn_affine(stats, gnw, gnb, NLAYERS - 1, b, tx, gw, gb);
    s_gw[tx] = gw; s_gb[tx] = gb;
  }
  __syncthreads();
  size_t zyx = (size_t)z * 4096 + y * 64 + tx;
  size_t base_b = (size_t)b * CW * NPTS;
  float hreg[24];
  for (int c = 0; c < 24; c++) hreg[c] = fmaf(h[base_b + (size_t)c * NPTS + zyx], s_gw[c], s_gb[c]);
  float acc = p2b[0];
  for (int o = 0; o < 24; o++) {
    float t = s_b[o];
#pragma unroll
    for (int c = 0; c < 24; c++) t += s_w[o * 24 + c] * hreg[c];
    acc += s_w2[o] * gelu_exact(t);
  }
  out[(size_t)b * NPTS + zyx] = acc;
}

extern "C" void kernel_launch(void* const* d_in, const int* in_sizes, int n_in,
                              void* d_out, int out_size, void* d_ws, size_t ws_size,
                              hipStream_t stream) {
  const float* xin    = (const float*)d_in[0];
  const float* lift_w = (const float*)d_in[1];
  const float* lift_b = (const float*)d_in[2];
  const float* spec_w = (const float*)d_in[3];
  const float* ws_w   = (const float*)d_in[4];
  const float* ws_b   = (const float*)d_in[5];
  const float* loc_w  = (const float*)d_in[6];
  const float* loc_b  = (const float*)d_in[7];
  const float* gn_w   = (const float*)d_in[8];
  const float* gn_b   = (const float*)d_in[9];
  const float* gammas = (const float*)d_in[10];
  const float* p1w    = (const float*)d_in[11];
  const float* p1b    = (const float*)d_in[12];
  const float* p2w    = (const float*)d_in[13];
  const float* p2b    = (const float*)d_in[14];
  float* ws = (float*)d_ws;
  float* out = (float*)d_out;

  float* stats = ws + OFF_STATS;
  float* state[2] = { ws + OFF_H, ws + OFF_PRE };

  // zero GN accumulators (ws is poisoned 0xAA before every launch)
  hipMemsetAsync(stats, 0, (NLAYERS * BN * 2) * sizeof(float), stream);

  k_axis<<<18, 256, 0, stream>>>(lift_w, ws);
  k_lift<<<BN * 4096, 64, 0, stream>>>(xin, lift_w, lift_b, ws);

  for (int l = 0; l < NLAYERS; l++) {
    const float* src = state[l & 1];
    float* dst = state[(l & 1) ^ 1];
    k_dftx<<<BN * CW * 64, 256, 0, stream>>>(src, ws + OFF_A1, stats, gn_w, gn_b, l);
    k_dftyz<<<BN * CW * 12, 256, 0, stream>>>(ws + OFF_A1, ws + OFF_HF);
    k_mix<<<BN * 54, 256, 0, stream>>>(ws + OFF_HF, spec_w, ws + OFF_OUT, l);
    k_invz<<<BN * CW * 4, 256, 0, stream>>>(ws + OFF_OUT, ws + OFF_A2);  // B1
    k_invy<<<BN * CW * 64, 256, 0, stream>>>(ws + OFF_A2, ws + OFF_A1);  // B2
    k_layer<<<BN * 1024, 256, 0, stream>>>(src, ws + OFF_A1, ws_w, ws_b, loc_w, loc_b,
                                           gammas, gn_w, gn_b, dst, stats, l);
  }
  k_proj<<<BN * 4096, 64, 0, stream>>>(state[0], p1w, p1b, p2w, p2b,
                                       stats, gn_w, gn_b, out);
}

// Round 10
// 1582.670 us; speedup vs baseline: 1.0834x; 1.0834x over previous
//
#include <hip/hip_runtime.h>
#include <hip/hip_bf16.h>
#include <math.h>

// FNO3D on MI355X. Inputs fp32, internal fp32, output fp32.
// B=4, C=24, 64^3 grid, modes 12^3, 4 layers.
// GroupNorm affine computed inline in consumers from raw stats (no gnstat pass).
// k_layer: round-8 proven structure (scalar FMA, single-channel stream, 24KB LDS).

static constexpr int BN = 4;
static constexpr int CW = 24;
static constexpr int ZD = 64;
static constexpr size_t NPTS = 64ull * 64 * 64;      // 262144
static constexpr int KM = 12;
static constexpr int KK2 = 144;
static constexpr int M3 = 1728;
static constexpr int NLAYERS = 4;
static constexpr float GN_N = 6291456.0f;            // CW*NPTS

static constexpr size_t OFF_H     = 0;                                     // state A [B][C][Z][Y][X]
static constexpr size_t OFF_PRE   = OFF_H   + (size_t)BN * CW * NPTS;      // state B (ping-pong)
static constexpr size_t OFF_A1    = OFF_PRE + (size_t)BN * CW * NPTS;      // A1 [b][c][z][kx][y] cplx (shared with B2 [b][o][z][y][kx])
static constexpr size_t OFF_A2    = OFF_A1  + (size_t)BN * CW * ZD * KM * ZD * 2; // B1 [b][o][z][kk] cplx
static constexpr size_t OFF_HF    = OFF_A2  + (size_t)BN * CW * KK2 * ZD * 2;     // Hf [b][c][mode] cplx
static constexpr size_t OFF_OUT   = OFF_HF  + (size_t)BN * CW * M3 * 2;           // Out [b][o][mode] cplx
static constexpr size_t OFF_AX    = OFF_OUT + (size_t)BN * CW * M3 * 2;           // axis tables 3*24*64
static constexpr size_t OFF_STATS = OFF_AX  + 3 * CW * 64;                        // [layer][b][2]

__device__ __forceinline__ float gelu_exact(float y) {
  return 0.5f * y * (1.f + erff(y * 0.70710678118654752f));
}

// per-(b,c) GN affine from raw stats of layer lm1 (lm1 < 0 -> identity)
__device__ __forceinline__ void gn_affine(const float* stats, const float* gnw,
                                          const float* gnb, int lm1, int b, int c,
                                          float& gw, float& gb) {
  gw = 1.f; gb = 0.f;
  if (lm1 >= 0) {
    float s1 = stats[(lm1 * BN + b) * 2];
    float s2 = stats[(lm1 * BN + b) * 2 + 1];
    float mean = s1 / GN_N;
    float var = s2 / GN_N - mean * mean;
    float rstd = rsqrtf(var + 1e-5f);
    gw = gnw[lm1 * CW + c] * rstd;
    gb = gnb[lm1 * CW + c] - mean * gw;
  }
}

// ---------------- axis tables for the lift (posenc is separable) -------------
__global__ void k_axis(const float* __restrict__ lw, float* __restrict__ ws) {
  int t = blockIdx.x * blockDim.x + threadIdx.x;
  if (t >= 3 * CW * 64) return;
  int v = t & 63;
  int o = (t >> 6) % CW;
  int axis = t / (64 * CW);
  float val = -1.f + 2.f * (float)v / 63.f;
  float acc = lw[o * 54 + 3 + axis] * val;   // linear coordinate channel
  for (int k = 1; k <= 8; k++) {
    float s, c;
    sincosf((float)k * 3.14159265358979323846f * val, &s, &c);
    int base = 6 + 6 * (k - 1) + 2 * axis;
    acc += lw[o * 54 + base] * s + lw[o * 54 + base + 1] * c;
  }
  ws[OFF_AX + (size_t)axis * CW * 64 + o * 64 + v] = acc;
}

// ---------------- lift: h = W*x + a_z + a_y + a_x + b (4-wave blocks) --------
__global__ __launch_bounds__(256) void k_lift(const float* __restrict__ xin,
                                              const float* __restrict__ lw,
                                              const float* __restrict__ lb,
                                              float* __restrict__ ws) {
  int bid = blockIdx.x;                  // b*1024 + z*16 + yt
  int b = bid >> 10, z = (bid >> 4) & 63, yt = bid & 15;
  int tid = threadIdx.x;
  int tx = tid & 63, ty = tid >> 6;
  int y = yt * 4 + ty;
  size_t zyx = (size_t)z * 4096 + y * 64 + tx;
  float x0 = xin[(size_t)(b * 3 + 0) * NPTS + zyx];
  float x1 = xin[(size_t)(b * 3 + 1) * NPTS + zyx];
  float x2 = xin[(size_t)(b * 3 + 2) * NPTS + zyx];
  const float* az = ws + OFF_AX;
  const float* ay = az + CW * 64;
  const float* axt = ay + CW * 64;
  float* h = ws + OFF_H;
  for (int o = 0; o < CW; o++) {
    float acc = lb[o] + lw[o * 54 + 0] * x0 + lw[o * 54 + 1] * x1 +
                lw[o * 54 + 2] * x2 + az[o * 64 + z] + ay[o * 64 + y] + axt[o * 64 + tx];
    h[(size_t)(b * CW + o) * NPTS + zyx] = acc;
  }
}

// ------- forward DFT along x (inline affine, register rotators) --------------
__global__ void k_dftx(const float* __restrict__ hsrc, float* __restrict__ A1,
                       const float* __restrict__ stats, const float* __restrict__ gnw,
                       const float* __restrict__ gnb, int layer) {
  __shared__ float pl[64][65];
  int bid = blockIdx.x;                  // bc*64 + z
  int bc = bid >> 6;
  float gw, gb;
  gn_affine(stats, gnw, gnb, layer - 1, bc / CW, bc % CW, gw, gb);
  const float* src = hsrc + (size_t)bid * 4096;
  int t = threadIdx.x;
  for (int i = t; i < 4096; i += 256) pl[i >> 6][i & 63] = fmaf(src[i], gw, gb);
  __syncthreads();
  int q = t >> 6, y = t & 63;            // thread computes modes kx = q, q+4, q+8 for row y
  float C0, S0, C1, S1, C2, S2;
  sincosf(-6.283185307179586f * (float)q / 64.f, &S0, &C0);
  sincosf(-6.283185307179586f * (float)(q + 4) / 64.f, &S1, &C1);
  sincosf(-6.283185307179586f * (float)(q + 8) / 64.f, &S2, &C2);
  float r0 = 1.f, i0 = 0.f, r1 = 1.f, i1 = 0.f, r2 = 1.f, i2 = 0.f;
  float ar0 = 0.f, ai0 = 0.f, ar1 = 0.f, ai1 = 0.f, ar2 = 0.f, ai2 = 0.f;
  const float* row = pl[y];
  for (int xx = 0; xx < 64; xx++) {
    float v = row[xx];
    ar0 = fmaf(v, r0, ar0); ai0 = fmaf(v, i0, ai0);
    ar1 = fmaf(v, r1, ar1); ai1 = fmaf(v, i1, ai1);
    ar2 = fmaf(v, r2, ar2); ai2 = fmaf(v, i2, ai2);
    float nr;
    nr = r0 * C0 - i0 * S0; i0 = fmaf(r0, S0, i0 * C0); r0 = nr;
    nr = r1 * C1 - i1 * S1; i1 = fmaf(r1, S1, i1 * C1); r1 = nr;
    nr = r2 * C2 - i2 * S2; i2 = fmaf(r2, S2, i2 * C2); r2 = nr;
  }
  float2* dst = (float2*)A1 + (size_t)bid * KM * 64;   // layout [kx][y]
  dst[t]       = make_float2(ar0, ai0);
  dst[t + 256] = make_float2(ar1, ai1);
  dst[t + 512] = make_float2(ar2, ai2);
}

// ------- fused forward DFT along y then z (one block per (bc,kx)) ------------
__global__ void k_dftyz(const float* __restrict__ A1, float* __restrict__ Hf) {
  __shared__ float in_re[64][65], in_im[64][65];
  __shared__ float o1_re[12][65], o1_im[12][65];
  int bid = blockIdx.x;                  // bc*12 + kx
  int kx = bid % 12, bc = bid / 12;
  int t = threadIdx.x;
  const float2* src = (const float2*)A1;
  for (int i = t; i < 4096; i += 256) {
    int z = i >> 6, y = i & 63;
    float2 v = src[((size_t)(bc * 64 + z)) * 768 + kx * 64 + y];
    in_re[z][y] = v.x; in_im[z][y] = v.y;
  }
  __syncthreads();
  // phase 1: y-DFT -> o1[ky][z]
  for (int i = t; i < 768; i += 256) {
    int z = i / 12, ky = i % 12;
    float C, S;
    sincosf(-6.283185307179586f * (float)ky / 64.f, &S, &C);
    float r = 1.f, ir = 0.f;
    float re = 0.f, im = 0.f;
    for (int y = 0; y < 64; y++) {
      float ar = in_re[z][y], ai = in_im[z][y];
      re += ar * r - ai * ir;
      im += ai * r + ar * ir;
      float nr = r * C - ir * S; ir = fmaf(r, S, ir * C); r = nr;
    }
    o1_re[ky][z] = re; o1_im[ky][z] = im;
  }
  __syncthreads();
  // phase 2: z-DFT -> Hf[kz][ky]
  if (t < KK2) {
    int kz = t / 12, ky = t % 12;
    float C, S;
    sincosf(-6.283185307179586f * (float)kz / 64.f, &S, &C);
    float r = 1.f, ir = 0.f;
    float re = 0.f, im = 0.f;
    for (int zz = 0; zz < 64; zz++) {
      float ar = o1_re[ky][zz], ai = o1_im[ky][zz];
      re += ar * r - ai * ir;
      im += ai * r + ar * ir;
      float nr = r * C - ir * S; ir = fmaf(r, S, ir * C); r = nr;
    }
    ((float2*)Hf)[(size_t)bc * M3 + kz * KK2 + ky * 12 + kx] = make_float2(re, im);
  }
}

// ---------------- mode mix: Out[b,o,m] = sum_c Hf[b,c,m]*W[c,o,m] ------------
__global__ void k_mix(const float* __restrict__ Hf, const float* __restrict__ specw,
                      float* __restrict__ Outb, int layer) {
  __shared__ float hre[24][64], him[24][64];
  int bid = blockIdx.x;                  // b*54 + chunk*2 + og
  int b = bid / 54, rem = bid % 54;
  int chunk = rem >> 1, og = rem & 1;
  int m0 = chunk * 64;
  int t = threadIdx.x;
  const float2* hf = (const float2*)Hf + (size_t)b * CW * M3;
  for (int i = t; i < 24 * 64; i += 256) {
    int c = i >> 6, m = i & 63;
    float2 v = hf[(size_t)c * M3 + m0 + m];
    hre[c][m] = v.x; him[c][m] = v.y;
  }
  __syncthreads();
  const float2* W2 = (const float2*)specw + (size_t)layer * 576 * M3;
  float2* outp = (float2*)Outb + (size_t)b * CW * M3;
  for (int p = t; p < 12 * 64; p += 256) {
    int o = og * 12 + (p >> 6), m = p & 63;
    int mg = m0 + m;
    float re = 0.f, im = 0.f;
    for (int c = 0; c < 24; c++) {
      float2 w = W2[(size_t)(c * 24 + o) * M3 + mg];
      float wr = w.x, wi = w.y;
      float ar = hre[c][m], ai = him[c][m];
      re += ar * wr - ai * wi;
      im += ar * wi + ai * wr;
    }
    int kx = mg % 12;
    float sc = (kx == 0 ? 1.f : 2.f) * (1.f / 262144.f);  // irfftn scale + rfft doubling
    outp[(size_t)o * M3 + mg] = make_float2(re * sc, im * sc);
  }
}

// ---------------- inverse DFT along z (register rotators) --------------------
__global__ void k_invz(const float* __restrict__ Outb, float* __restrict__ B1) {
  __shared__ float lre[1728], lim[1728];
  int bid = blockIdx.x;                  // bo*4 + zc
  int bo = bid >> 2, zc = bid & 3;
  const float2* src = (const float2*)Outb + (size_t)bo * M3;
  int t = threadIdx.x;
  for (int i = t; i < 1728; i += 256) { float2 v = src[i]; lre[i] = v.x; lim[i] = v.y; }
  __syncthreads();
  float2* dst = (float2*)B1 + (size_t)bo * 64 * KK2 + (size_t)zc * 16 * KK2;
  for (int p = t; p < 16 * KK2; p += 256) {
    int z = zc * 16 + p / KK2, kk = p % KK2;
    float C, S;
    sincosf(6.283185307179586f * (float)z / 64.f, &S, &C);
    float r = 1.f, ir = 0.f;
    float re = 0.f, im = 0.f;
    for (int kz = 0; kz < 12; kz++) {
      float ar = lre[kz * KK2 + kk], ai = lim[kz * KK2 + kk];
      re += ar * r - ai * ir;
      im += ar * ir + ai * r;
      float nr = r * C - ir * S; ir = fmaf(r, S, ir * C); r = nr;
    }
    dst[p] = make_float2(re, im);
  }
}

// ---------------- inverse DFT along y (register rotators) --------------------
__global__ void k_invy(const float* __restrict__ B1, float* __restrict__ B2) {
  __shared__ float lre[144], lim[144];
  int bid = blockIdx.x;                  // bo*64 + z
  const float2* src = (const float2*)B1 + (size_t)bid * KK2;
  int t = threadIdx.x;
  if (t < 144) { float2 v = src[t]; lre[t] = v.x; lim[t] = v.y; }
  __syncthreads();
  float2* dst = (float2*)B2 + (size_t)bid * 64 * KM;
  for (int p = t; p < 64 * KM; p += 256) {
    int y = p / KM, kx = p % KM;
    float C, S;
    sincosf(6.283185307179586f * (float)y / 64.f, &S, &C);
    float r = 1.f, ir = 0.f;
    float re = 0.f, im = 0.f;
    for (int ky = 0; ky < 12; ky++) {
      float ar = lre[ky * 12 + kx], ai = lim[ky * 12 + kx];
      re += ar * r - ai * ir;
      im += ar * ir + ai * r;
      float nr = r * C - ir * S; ir = fmaf(r, S, ir * C); r = nr;
    }
    dst[p] = make_float2(re, im);        // p = y*12+kx -> layout [y][kx]
  }
}

// ------- fused: affine-on-load + inverse-x + ws conv + depthwise + gelu +
//         residual + GN sums. Round-8 structure (single-channel stream). ------
__global__ __launch_bounds__(256) void k_layer(const float* __restrict__ hsrc,
                                               const float* __restrict__ B2f,
                                               const float* __restrict__ wsw,
                                               const float* __restrict__ wsb,
                                               const float* __restrict__ locw,
                                               const float* __restrict__ locb,
                                               const float* __restrict__ gammas,
                                               const float* __restrict__ gnw,
                                               const float* __restrict__ gnb,
                                               float* __restrict__ pre,
                                               float* __restrict__ stats, int layer) {
  __shared__ __align__(16) float s_ws[576];
  __shared__ float s_loc[648];
  __shared__ __align__(16) float s_sp[2304];   // [o][ty][kx][2]
  __shared__ float s_wsb[24], s_locb[24];
  __shared__ float s_gw[24], s_gb[24];
  __shared__ float s_ch[2][18][66];      // dbuf halo tile [3z x 6y][x padded], cols 0 & 65 = 0
  __shared__ float s_red[8];

  int bid = blockIdx.x;                  // b*1024 + z*16 + yt
  int b = bid >> 10, z = (bid >> 4) & 63, yt = bid & 15;
  int y0 = yt * 4;
  int tid = threadIdx.x;
  int tx = tid & 63, ty = tid >> 6;      // each wave handles one y-row
  int y = y0 + ty;

  for (int i = tid; i < 576; i += 256) s_ws[i] = wsw[layer * 576 + i];
  for (int i = tid; i < 648; i += 256) s_loc[i] = locw[layer * 648 + i];
  const float2* b2 = (const float2*)B2f;
  for (int i = tid; i < 1152; i += 256) {              // 24o * 4ty * 12kx float2
    int o = i / 48, rem = i % 48;
    int tyy = rem / 12, kxx = rem % 12;
    float2 v = b2[(((size_t)(b * CW + o) * 64 + z) * 64 + (y0 + tyy)) * KM + kxx];
    s_sp[((o * 4 + tyy) * 12 + kxx) * 2]     = v.x;
    s_sp[((o * 4 + tyy) * 12 + kxx) * 2 + 1] = v.y;
  }
  if (tid < 24) {
    s_wsb[tid] = wsb[layer * 24 + tid]; s_locb[tid] = locb[layer * 24 + tid];
    float gw, gb;
    gn_affine(stats, gnw, gnb, layer - 1, b, tid, gw, gb);
    s_gw[tid] = gw; s_gb[tid] = gb;
  }
  if (tid < 72) {                        // zero the x-halo columns (both buffers)
    int bf = tid / 36, rem = tid % 36;
    s_ch[bf][rem >> 1][(rem & 1) * 65] = 0.f;
  }
  __syncthreads();                       // s_gw/s_gb + halo zeros visible

  // per-thread register twiddles (no LDS bank conflicts)
  float cs[12], sn[12];
#pragma unroll
  for (int k = 0; k < 12; k++) {
    sincosf(6.283185307179586f * (float)((k * tx) & 63) / 64.f, &sn[k], &cs[k]);
  }

  float gamma = gammas[layer];
  size_t base_b = (size_t)b * CW * NPTS;
  size_t zyx = (size_t)z * 4096 + (size_t)y * 64 + tx;

  // center values for all channels (pointwise input), affine applied
  float hreg[24];
#pragma unroll
  for (int c = 0; c < 24; c++) hreg[c] = fmaf(hsrc[base_b + (size_t)c * NPTS + zyx], s_gw[c], s_gb[c]);

  // staging geometry (i = tid + j*256 < 1152): rr=i>>6 -> zi=rr/6, yi=rr%6
  int si[5]; size_t sgo[5]; bool svalid[5];
#pragma unroll
  for (int j = 0; j < 5; j++) {
    int i = tid + j * 256;
    si[j] = i;
    int rr = i >> 6, xx = i & 63;
    int z2 = z + rr / 6 - 1, y2 = y0 + (rr % 6) - 1;
    svalid[j] = (i < 1152) && ((unsigned)z2 < 64u) && ((unsigned)y2 < 64u);
    sgo[j] = (size_t)((unsigned)z2 & 63u) * 4096 + (size_t)((unsigned)y2 & 63u) * 64 + xx;
  }

  // prologue: stage channel 0 (affine'd) into buf 0
#pragma unroll
  for (int j = 0; j < 5; j++) {
    float v = svalid[j] ? fmaf(hsrc[base_b + sgo[j]], s_gw[0], s_gb[0]) : 0.f;
    if (si[j] < 1152) s_ch[0][si[j] >> 6][(si[j] & 63) + 1] = v;
  }
  __syncthreads();

  float lsum = 0.f, lsq = 0.f;
  int cur = 0;
  for (int o = 0; o < 24; o++) {
    // (a) issue next channel's loads early (latency hides under compute)
    float r0 = 0.f, r1 = 0.f, r2 = 0.f, r3 = 0.f, r4 = 0.f;
    if (o < 23) {
      size_t nb = base_b + (size_t)(o + 1) * NPTS;
      if (svalid[0]) r0 = hsrc[nb + sgo[0]];
      if (svalid[1]) r1 = hsrc[nb + sgo[1]];
      if (svalid[2]) r2 = hsrc[nb + sgo[2]];
      if (svalid[3]) r3 = hsrc[nb + sgo[3]];
      if (svalid[4]) r4 = hsrc[nb + sgo[4]];
    }

    // (b) compute output channel o from s_ch[cur]
    float hc = s_ch[cur][7 + ty][1 + tx];    // center (zi=1, yi=1)
    // depthwise 3x3x3: direct padded-LDS reads, no shfl
    float dv = 0.f;
#pragma unroll
    for (int zi = 0; zi < 3; zi++) {
#pragma unroll
      for (int yi = 0; yi < 3; yi++) {
        const float* row = &s_ch[cur][zi * 6 + ty + yi][1 + tx];
        int wb = (zi * 3 + yi) * 3;
        dv += row[-1] * s_loc[o * 27 + wb] + row[0] * s_loc[o * 27 + wb + 1] + row[1] * s_loc[o * 27 + wb + 2];
      }
    }
    // pointwise 24x24: wide LDS broadcast reads (6 x ds_read_b128)
    const float4* wsv = (const float4*)&s_ws[o * 24];
    float4 wa0 = wsv[0], wa1 = wsv[1], wa2 = wsv[2], wa3 = wsv[3], wa4 = wsv[4], wa5 = wsv[5];
    float wv = wa0.x * hreg[0]  + wa0.y * hreg[1]  + wa0.z * hreg[2]  + wa0.w * hreg[3]
             + wa1.x * hreg[4]  + wa1.y * hreg[5]  + wa1.z * hreg[6]  + wa1.w * hreg[7]
             + wa2.x * hreg[8]  + wa2.y * hreg[9]  + wa2.z * hreg[10] + wa2.w * hreg[11]
             + wa3.x * hreg[12] + wa3.y * hreg[13] + wa3.z * hreg[14] + wa3.w * hreg[15]
             + wa4.x * hreg[16] + wa4.y * hreg[17] + wa4.z * hreg[18] + wa4.w * hreg[19]
             + wa5.x * hreg[20] + wa5.y * hreg[21] + wa5.z * hreg[22] + wa5.w * hreg[23];
    // spectral inverse along x: wide LDS broadcast reads (6 x ds_read_b128)
    const float4* spv = (const float4*)&s_sp[(o * 4 + ty) * 24];
    float4 p0 = spv[0], p1 = spv[1], p2 = spv[2], p3 = spv[3], p4 = spv[4], p5 = spv[5];
    float sp = p0.x * cs[0]  - p0.y * sn[0]  + p0.z * cs[1]  - p0.w * sn[1]
             + p1.x * cs[2]  - p1.y * sn[2]  + p1.z * cs[3]  - p1.w * sn[3]
             + p2.x * cs[4]  - p2.y * sn[4]  + p2.z * cs[5]  - p2.w * sn[5]
             + p3.x * cs[6]  - p3.y * sn[6]  + p3.z * cs[7]  - p3.w * sn[7]
             + p4.x * cs[8]  - p4.y * sn[8]  + p4.z * cs[9]  - p4.w * sn[9]
             + p5.x * cs[10] - p5.y * sn[10] + p5.z * cs[11] - p5.w * sn[11];
    float yv = sp + wv + s_wsb[o] + dv + s_locb[o];
    float pv = hc + gamma * gelu_exact(yv);
    pre[base_b + (size_t)o * NPTS + zyx] = pv;
    lsum += pv; lsq += pv * pv;

    // (c) write staged values (affine'd) into the other buffer, then barrier
    if (o < 23) {
      int nbuf = cur ^ 1;
      float gwn = s_gw[o + 1], gbn = s_gb[o + 1];
      float w0 = svalid[0] ? fmaf(r0, gwn, gbn) : 0.f;
      float w1 = svalid[1] ? fmaf(r1, gwn, gbn) : 0.f;
      float w2 = svalid[2] ? fmaf(r2, gwn, gbn) : 0.f;
      float w3 = svalid[3] ? fmaf(r3, gwn, gbn) : 0.f;
      float w4 = svalid[4] ? fmaf(r4, gwn, gbn) : 0.f;
      if (si[0] < 1152) s_ch[nbuf][si[0] >> 6][(si[0] & 63) + 1] = w0;
      if (si[1] < 1152) s_ch[nbuf][si[1] >> 6][(si[1] & 63) + 1] = w1;
      if (si[2] < 1152) s_ch[nbuf][si[2] >> 6][(si[2] & 63) + 1] = w2;
      if (si[3] < 1152) s_ch[nbuf][si[3] >> 6][(si[3] & 63) + 1] = w3;
      if (si[4] < 1152) s_ch[nbuf][si[4] >> 6][(si[4] & 63) + 1] = w4;
    }
    __syncthreads();
    cur ^= 1;
  }

  for (int off = 32; off; off >>= 1) { lsum += __shfl_down(lsum, off); lsq += __shfl_down(lsq, off); }
  if (tx == 0) { s_red[ty * 2] = lsum; s_red[ty * 2 + 1] = lsq; }
  __syncthreads();
  if (tid == 0) {
    float a = s_red[0] + s_red[2] + s_red[4] + s_red[6];
    float q = s_red[1] + s_red[3] + s_red[5] + s_red[7];
    atomicAdd(&stats[(layer * BN + b) * 2], a);
    atomicAdd(&stats[(layer * BN + b) * 2 + 1], q);
  }
}

// ---------------- projection head (inline affine, 4-wave blocks) -------------
__global__ __launch_bounds__(256) void k_proj(const float* __restrict__ h,
                                              const float* __restrict__ p1w,
                                              const float* __restrict__ p1b,
                                              const float* __restrict__ p2w,
                                              const float* __restrict__ p2b,
                                              const float* __restrict__ stats,
                                              const float* __restrict__ gnw,
                                              const float* __restrict__ gnb,
                                              float* __restrict__ out) {
  __shared__ float s_w[576], s_b[24], s_w2[24], s_gw[24], s_gb[24];
  int bid = blockIdx.x;                  // b*1024 + z*16 + yt
  int b = bid >> 10, z = (bid >> 4) & 63, yt = bid & 15;
  int tid = threadIdx.x;
  int tx = tid & 63, ty = tid >> 6;
  int y = yt * 4 + ty;
  for (int i = tid; i < 576; i += 256) s_w[i] = p1w[i];
  if (tid < 24) {
    s_b[tid] = p1b[tid]; s_w2[tid] = p2w[tid];
    float gw, gb;
    gn_affine(stats, gnw, gnb, NLAYERS - 1, b, tid, gw, gb);
    s_gw[tid] = gw; s_gb[tid] = gb;
  }
  __syncthreads();
  size_t zyx = (size_t)z * 4096 + (size_t)y * 64 + tx;
  size_t base_b = (size_t)b * CW * NPTS;
  float hreg[24];
#pragma unroll
  for (int c = 0; c < 24; c++) hreg[c] = fmaf(h[base_b + (size_t)c * NPTS + zyx], s_gw[c], s_gb[c]);
  float acc = p2b[0];
  for (int o = 0; o < 24; o++) {
    float t = s_b[o];
#pragma unroll
    for (int c = 0; c < 24; c++) t += s_w[o * 24 + c] * hreg[c];
    acc += s_w2[o] * gelu_exact(t);
  }
  out[(size_t)b * NPTS + zyx] = acc;
}

extern "C" void kernel_launch(void* const* d_in, const int* in_sizes, int n_in,
                              void* d_out, int out_size, void* d_ws, size_t ws_size,
                              hipStream_t stream) {
  const float* xin    = (const float*)d_in[0];
  const float* lift_w = (const float*)d_in[1];
  const float* lift_b = (const float*)d_in[2];
  const float* spec_w = (const float*)d_in[3];
  const float* ws_w   = (const float*)d_in[4];
  const float* ws_b   = (const float*)d_in[5];
  const float* loc_w  = (const float*)d_in[6];
  const float* loc_b  = (const float*)d_in[7];
  const float* gn_w   = (const float*)d_in[8];
  const float* gn_b   = (const float*)d_in[9];
  const float* gammas = (const float*)d_in[10];
  const float* p1w    = (const float*)d_in[11];
  const float* p1b    = (const float*)d_in[12];
  const float* p2w    = (const float*)d_in[13];
  const float* p2b    = (const float*)d_in[14];
  float* ws = (float*)d_ws;
  float* out = (float*)d_out;

  float* stats = ws + OFF_STATS;
  float* state[2] = { ws + OFF_H, ws + OFF_PRE };

  // zero GN accumulators (ws is poisoned 0xAA before every launch)
  hipMemsetAsync(stats, 0, (NLAYERS * BN * 2) * sizeof(float), stream);

  k_axis<<<18, 256, 0, stream>>>(lift_w, ws);
  k_lift<<<BN * 1024, 256, 0, stream>>>(xin, lift_w, lift_b, ws);

  for (int l = 0; l < NLAYERS; l++) {
    const float* src = state[l & 1];
    float* dst = state[(l & 1) ^ 1];
    k_dftx<<<BN * CW * 64, 256, 0, stream>>>(src, ws + OFF_A1, stats, gn_w, gn_b, l);
    k_dftyz<<<BN * CW * 12, 256, 0, stream>>>(ws + OFF_A1, ws + OFF_HF);
    k_mix<<<BN * 54, 256, 0, stream>>>(ws + OFF_HF, spec_w, ws + OFF_OUT, l);
    k_invz<<<BN * CW * 4, 256, 0, stream>>>(ws + OFF_OUT, ws + OFF_A2);  // B1
    k_invy<<<BN * CW * 64, 256, 0, stream>>>(ws + OFF_A2, ws + OFF_A1);  // B2
    k_layer<<<BN * 1024, 256, 0, stream>>>(src, ws + OFF_A1, ws_w, ws_b, loc_w, loc_b,
                                           gammas, gn_w, gn_b, dst, stats, l);
  }
  k_proj<<<BN * 1024, 256, 0, stream>>>(state[0], p1w, p1b, p2w, p2b,
                                        stats, gn_w, gn_b, out);
}